// Round 15
// baseline (371.527 us; speedup 1.0000x reference)
//
#include <hip/hip_runtime.h>
#include <math.h>

constexpr int Nn  = 65536;    // nodes
constexpr int Ne  = 1048576;  // edges
constexpr int Bg  = 256;      // graphs
constexpr int DIN = 32;
constexpr int D   = 64;

constexpr int NB   = 256;     // dst buckets (dst>>8)
constexpr int BCAP = 6144;    // bucket stream capacity (mean 4096, +36 sigma)

typedef __attribute__((ext_vector_type(8))) short bf16x8;
typedef __attribute__((ext_vector_type(8))) unsigned short u16x8;
typedef __attribute__((ext_vector_type(4))) float f32x4;

__device__ __forceinline__ float sigf(float x) { return 1.0f / (1.0f + expf(-x)); }

// ---- bf16 split helpers (RNE) ----
__device__ __forceinline__ unsigned short bf16_rne(float f) {
  unsigned u = __float_as_uint(f);
  unsigned r = u + 0x7FFFu + ((u >> 16) & 1u);
  return (unsigned short)(r >> 16);
}
__device__ __forceinline__ float bf16_tof(unsigned short h) {
  return __uint_as_float(((unsigned)h) << 16);
}
__device__ __forceinline__ void split2(float f, unsigned short& hi, unsigned short& lo) {
  hi = bf16_rne(f);
  lo = bf16_rne(f - bf16_tof(hi));
}
__device__ __forceinline__ float recon(unsigned short hi, unsigned short lo) {
  return bf16_tof(hi) + bf16_tof(lo);
}

#define MFMA(a, b, c) __builtin_amdgcn_mfma_f32_16x16x32_bf16(a, b, c, 0, 0, 0)

// ---------------------------------------------------------------------------
// Prep.  GRU weights chunk-major (5 chunks x 12nt x 64lane x 8j / plane):
//   chunks 0,1 = Wfold = Wih[:, :64] @ W_conv   (fused conv-linear)
//   chunk  2   = Wih[:, 64:96]  (x part)
//   chunks 3,4 = Whh
// Also: W_mlp pack, LSTM/W1 transposes, graphptr, rp[Nn], vfold.
// ---------------------------------------------------------------------------
__global__ void k_prepw(const float* __restrict__ W_mlp, const float* __restrict__ W_conv,
                        const float* __restrict__ gWih, const float* __restrict__ gWhh,
                        const float* __restrict__ b_conv,
                        const float* __restrict__ lW_ih, const float* __restrict__ lW_hh,
                        const float* __restrict__ W1,
                        unsigned short* __restrict__ mlp_h, unsigned short* __restrict__ mlp_l,
                        unsigned short* __restrict__ gw_h,  unsigned short* __restrict__ gw_l,
                        float* __restrict__ WihT, float* __restrict__ WhhT,
                        float* __restrict__ W1T, float* __restrict__ vfold,
                        const int* __restrict__ batch, int* __restrict__ gp,
                        int* __restrict__ rp) {
  int idx = blockIdx.x * 256 + threadIdx.x;
  if (idx < 30720) {  // GRU weights, chunk-major
    int c = idx / 6144, rem = idx % 6144;
    int nt = rem >> 9, lane = (rem >> 3) & 63, j = rem & 7;
    int n = nt * 16 + (lane & 15);
    int kk = c * 32 + (lane >> 4) * 8 + j;   // for c<3: k index into [S|x]
    float v;
    if (c < 2) {        // Wfold[n][kk] = sum_o Wih[n][o] * W_conv[o][kk]
      float s = 0.f;
      for (int o = 0; o < 64; ++o) s = fmaf(gWih[n * 96 + o], W_conv[o * 64 + kk], s);
      v = s;
    } else if (c == 2) {
      v = gWih[n * 96 + kk];                 // kk in 64..95 (x columns)
    } else {
      v = gWhh[n * 64 + (c - 3) * 32 + (lane >> 4) * 8 + j];
    }
    unsigned short hi, lo; split2(v, hi, lo);
    gw_h[idx] = hi; gw_l[idx] = lo;
    return;
  }
  if (idx < 32768) {  // W_mlp (KS=1)
    int lp = idx - 30720;
    int nt = lp >> 9, lane = (lp >> 3) & 63, j = lp & 7;
    int n = nt * 16 + (lane & 15);
    unsigned short hi, lo;
    split2(W_mlp[n * 32 + (lane >> 4) * 8 + j], hi, lo);
    mlp_h[lp] = hi; mlp_l[lp] = lo;
    return;
  }
  int t = idx - 32768;
  if (t < 32768) {                 // lstm W_ih [256][128] -> WihT [128][256]
    int row = t / 128, k = t % 128;
    WihT[k * 256 + row] = lW_ih[t];
  } else if (t < 49152) {          // lstm W_hh [256][64] -> WhhT [64][256]
    int j = t - 32768;
    int row = j / 64, k = j % 64;
    WhhT[k * 256 + row] = lW_hh[j];
  } else if (t < 57344) {          // W1 [64][128] -> W1T [128][64]
    int j = t - 49152;
    int row = j / 128, k = j % 128;
    W1T[k * 64 + row] = W1[j];
  } else if (t < 57344 + Bg + 1) { // graphptr + rp[Nn]
    int g = t - 57344;
    if (g == 0) rp[Nn] = Ne;
    int lo = 0, hi = Nn;
    while (lo < hi) {
      int mid = (lo + hi) >> 1;
      if (batch[mid] < g) lo = mid + 1; else hi = mid;
    }
    gp[g] = lo;
  } else if (t < 57344 + 257 + 192) { // vfold[192]
    int g = t - 57344 - 257;
    float s = 0.f;
    for (int o = 0; o < 64; ++o) s = fmaf(gWih[g * 96 + o], b_conv[o], s);
    vfold[g] = s;
  }
}

// ---------------------------------------------------------------------------
// conv1: h = x @ W_mlp^T + b  (K=32, N=64). Splits x in-kernel; also fills
// inp96 x-columns (64..95).  h stored as planes only.
// ---------------------------------------------------------------------------
__global__ __launch_bounds__(256) void k_conv1(const float* __restrict__ x,
                                               const unsigned short* __restrict__ Wh,
                                               const unsigned short* __restrict__ Wl,
                                               const float* __restrict__ bias,
                                               unsigned short* __restrict__ hph,
                                               unsigned short* __restrict__ hpl,
                                               unsigned short* __restrict__ Aih,
                                               unsigned short* __restrict__ Ail) {
  int wave = threadIdx.x >> 6, lane = threadIdx.x & 63;
  int quad = lane >> 4;
  int n0w = blockIdx.x * 64 + wave * 16;
  int rowA = n0w + (lane & 15);
  const float4* xp = (const float4*)&x[(size_t)rowA * 32 + quad * 8];
  float4 xa = xp[0], xb = xp[1];
  float xv[8] = {xa.x, xa.y, xa.z, xa.w, xb.x, xb.y, xb.z, xb.w};
  bf16x8 ah, al;
#pragma unroll
  for (int j = 0; j < 8; ++j) {
    unsigned short hi, lo; split2(xv[j], hi, lo);
    ah[j] = (short)hi; al[j] = (short)lo;
  }
  *(bf16x8*)&Aih[(size_t)rowA * 96 + 64 + quad * 8] = ah;
  *(bf16x8*)&Ail[(size_t)rowA * 96 + 64 + quad * 8] = al;

  f32x4 acc[4] = {};
#pragma unroll
  for (int nt = 0; nt < 4; ++nt) {
    bf16x8 bh = *(const bf16x8*)&Wh[(nt * 64 + lane) * 8];
    bf16x8 bl = *(const bf16x8*)&Wl[(nt * 64 + lane) * 8];
    acc[nt] = MFMA(ah, bh, acc[nt]);
    acc[nt] = MFMA(ah, bl, acc[nt]);
    acc[nt] = MFMA(al, bh, acc[nt]);
  }
  int col0 = lane & 15;
#pragma unroll
  for (int nt = 0; nt < 4; ++nt) {
    float bv = bias[nt * 16 + col0];
#pragma unroll
    for (int r = 0; r < 4; ++r) {
      int node = n0w + quad * 4 + r;
      float v = acc[nt][r] + bv;
      size_t o = (size_t)node * 64 + nt * 16 + col0;
      unsigned short hi, lo; split2(v, hi, lo);
      hph[o] = hi; hpl[o] = lo;
    }
  }
}

// ---------------------------------------------------------------------------
// Fused GRU v8: aggregate fused in (round-14 structure) at 3 blocks/CU.
// LDS 48 KB/block x 3 = 144 KB <= 160 KB; VGPR 124 <= ~170 cap at 3 waves/EU.
// ---------------------------------------------------------------------------
__global__ __launch_bounds__(256, 3) void k_gru(const unsigned short* __restrict__ Aih,
                                                const unsigned short* __restrict__ Ail,
                                                const unsigned short* __restrict__ Hh,
                                                const unsigned short* __restrict__ Hl,
                                                const unsigned short* __restrict__ gw_h,
                                                const unsigned short* __restrict__ gw_l,
                                                const float* __restrict__ b_ih,
                                                const float* __restrict__ b_hh,
                                                const float* __restrict__ vfold,
                                                const int* __restrict__ rp,
                                                const int* __restrict__ srcs,
                                                unsigned short* __restrict__ nph,
                                                unsigned short* __restrict__ npl) {
  __shared__ unsigned short sW[2][12288];  // per buf: hi[0..6143] | lo[6144..]
  int tid = threadIdx.x;
  int wave = tid >> 6, lane = tid & 63;
  int quad = lane >> 4;
  int n0w = blockIdx.x * 128 + wave * 32;
  int rowA0 = n0w + (lane & 15);          // tile0 A-row; tile1 = +16

  // ---- fused aggregate: gather S fragments for chunks 0,1, both tiles ----
  bf16x8 fh[2][2], fl[2][2];  // [tile][chunk]
#pragma unroll
  for (int tile = 0; tile < 2; ++tile) {
    int row = rowA0 + tile * 16;
    int s = rp[row], e = rp[row + 1];
    float acc0[8] = {}, acc1[8] = {};
    for (int i = s; i < e; ++i) {
      int src = srcs[i];
      u16x8 v0 = *(const u16x8*)&Hh[(size_t)src * 64 + quad * 8];
      u16x8 v1 = *(const u16x8*)&Hh[(size_t)src * 64 + 32 + quad * 8];
#pragma unroll
      for (int j = 0; j < 8; ++j) {
        acc0[j] += bf16_tof(v0[j]);
        acc1[j] += bf16_tof(v1[j]);
      }
    }
#pragma unroll
    for (int j = 0; j < 8; ++j) {
      unsigned short hi, lo;
      split2(acc0[j], hi, lo);
      fh[tile][0][j] = (short)hi; fl[tile][0][j] = (short)lo;
      split2(acc1[j], hi, lo);
      fh[tile][1][j] = (short)hi; fl[tile][1][j] = (short)lo;
    }
  }

  f32x4 acc0[12] = {}, acc1[12] = {};     // gi r,z,n (gh r,z folded into 0..7)
  f32x4 aN0[4] = {}, aN1[4] = {};         // gh n-gate

  // prologue: weights chunk 0
  bf16x8 gvh[3], gvl[3];
#pragma unroll
  for (int j = 0; j < 3; ++j) {
    gvh[j] = *(const bf16x8*)&gw_h[(tid + j * 256) * 8];
    gvl[j] = *(const bf16x8*)&gw_l[(tid + j * 256) * 8];
  }
#pragma unroll
  for (int j = 0; j < 3; ++j) {
    *(bf16x8*)&sW[0][(tid + j * 256) * 8] = gvh[j];
    *(bf16x8*)&sW[0][6144 + (tid + j * 256) * 8] = gvl[j];
  }
  __syncthreads();

#pragma unroll
  for (int c = 0; c < 5; ++c) {
    const int buf = c & 1;
    if (c < 4) {  // prefetch chunk c+1 weights
#pragma unroll
      for (int j = 0; j < 3; ++j) {
        gvh[j] = *(const bf16x8*)&gw_h[(c + 1) * 6144 + (tid + j * 256) * 8];
        gvl[j] = *(const bf16x8*)&gw_l[(c + 1) * 6144 + (tid + j * 256) * 8];
      }
    }
    // A fragments
    bf16x8 a0h, a0l, a1h, a1l;
    if (c < 2) {            // gathered S fragments (registers)
      a0h = fh[0][c]; a0l = fl[0][c];
      a1h = fh[1][c]; a1l = fl[1][c];
    } else if (c == 2) {    // x columns from conv1 prep
      size_t b0 = (size_t)rowA0 * 96 + 64 + quad * 8;
      size_t b1 = (size_t)(rowA0 + 16) * 96 + 64 + quad * 8;
      a0h = *(const bf16x8*)&Aih[b0]; a0l = *(const bf16x8*)&Ail[b0];
      a1h = *(const bf16x8*)&Aih[b1]; a1l = *(const bf16x8*)&Ail[b1];
    } else {                // h planes (Whh chunks)
      size_t b0 = (size_t)rowA0 * 64 + (c - 3) * 32 + quad * 8;
      size_t b1 = (size_t)(rowA0 + 16) * 64 + (c - 3) * 32 + quad * 8;
      a0h = *(const bf16x8*)&Hh[b0]; a0l = *(const bf16x8*)&Hl[b0];
      a1h = *(const bf16x8*)&Hh[b1]; a1l = *(const bf16x8*)&Hl[b1];
    }
    const unsigned short* sw = sW[buf];
#pragma unroll
    for (int nt = 0; nt < 12; ++nt) {
      bf16x8 bh = *(const bf16x8*)&sw[(nt * 64 + lane) * 8];
      bf16x8 bl = *(const bf16x8*)&sw[6144 + (nt * 64 + lane) * 8];
      if (c < 3 || nt < 8) {
        acc0[nt] = MFMA(a0h, bh, acc0[nt]);
        acc0[nt] = MFMA(a0h, bl, acc0[nt]);
        acc0[nt] = MFMA(a0l, bh, acc0[nt]);
        acc1[nt] = MFMA(a1h, bh, acc1[nt]);
        acc1[nt] = MFMA(a1h, bl, acc1[nt]);
        acc1[nt] = MFMA(a1l, bh, acc1[nt]);
      } else {
        aN0[nt - 8] = MFMA(a0h, bh, aN0[nt - 8]);
        aN0[nt - 8] = MFMA(a0h, bl, aN0[nt - 8]);
        aN0[nt - 8] = MFMA(a0l, bh, aN0[nt - 8]);
        aN1[nt - 8] = MFMA(a1h, bh, aN1[nt - 8]);
        aN1[nt - 8] = MFMA(a1h, bl, aN1[nt - 8]);
        aN1[nt - 8] = MFMA(a1l, bh, aN1[nt - 8]);
      }
    }
    if (c < 4) {
#pragma unroll
      for (int j = 0; j < 3; ++j) {
        *(bf16x8*)&sW[1 - buf][(tid + j * 256) * 8] = gvh[j];
        *(bf16x8*)&sW[1 - buf][6144 + (tid + j * 256) * 8] = gvl[j];
      }
    }
    __syncthreads();
  }

  // epilogue: GRU nonlinearity + deg*vfold (folded conv bias) + plane store
  int col0 = lane & 15;
#pragma unroll
  for (int tile = 0; tile < 2; ++tile) {
    int nb = n0w + tile * 16;
#pragma unroll
    for (int r = 0; r < 4; ++r) {
      int node = nb + quad * 4 + r;
      float degf = (float)(rp[node + 1] - rp[node]);
#pragma unroll
      for (int nt = 0; nt < 4; ++nt) {
        int g = nt * 16 + col0;
        size_t o = (size_t)node * 64 + g;
        float br  = b_ih[g] + b_hh[g] + degf * vfold[g];
        float bz  = b_ih[64 + g] + b_hh[64 + g] + degf * vfold[64 + g];
        float bin = b_ih[128 + g] + degf * vfold[128 + g];
        float bhn = b_hh[128 + g];
        float gr = tile ? acc1[nt][r]     : acc0[nt][r];
        float gz = tile ? acc1[nt + 4][r] : acc0[nt + 4][r];
        float gn = tile ? acc1[nt + 8][r] : acc0[nt + 8][r];
        float hn = tile ? aN1[nt][r]      : aN0[nt][r];
        float rr = sigf(gr + br);
        float zz = sigf(gz + bz);
        float nn = tanhf(gn + bin + rr * (hn + bhn));
        float h_old = recon(Hh[o], Hl[o]);
        float hv = (1.f - zz) * nn + zz * h_old;
        unsigned short hi, lo; split2(hv, hi, lo);
        nph[o] = hi; npl[o] = lo;
      }
    }
  }
}

// ---------------------------------------------------------------------------
// CSR build v3: two-level bucket sort by dst.
// ---------------------------------------------------------------------------
__global__ __launch_bounds__(256) void k_bucket(const int* __restrict__ eidx,
                                                int* __restrict__ gcur,     // [NB*16]
                                                int* __restrict__ payload) {// [NB*BCAP]
  __shared__ int lcnt[NB];
  __shared__ int lcur[NB];
  int t = threadIdx.x;
  int e0 = blockIdx.x * 4096;
  lcnt[t] = 0;
  __syncthreads();
  int ds[16], ss[16];
#pragma unroll
  for (int i = 0; i < 16; ++i) {
    int e = e0 + i * 256 + t;
    ds[i] = eidx[Ne + e];
    ss[i] = eidx[e];
    atomicAdd(&lcnt[ds[i] >> 8], 1);
  }
  __syncthreads();
  lcur[t] = atomicAdd(&gcur[t * 16], lcnt[t]);  // reserve contiguous run
  __syncthreads();
#pragma unroll
  for (int i = 0; i < 16; ++i) {
    int b = ds[i] >> 8;
    int p = atomicAdd(&lcur[b], 1);
    if (p < BCAP) payload[b * BCAP + p] = (ss[i] << 8) | (ds[i] & 255);
  }
}

// One block per bucket: inline scan of gcur -> base, LDS hist -> rp slice,
// place srcs via LDS cursors (scatter window owned by one CU).
__global__ __launch_bounds__(256) void k_placeB(const int* __restrict__ gcur,
                                                const int* __restrict__ payload,
                                                int* __restrict__ rp,
                                                int* __restrict__ srcs) {
  __shared__ int sAll[NB];
  __shared__ int hst[NB];
  __shared__ int cur[NB];
  int b = blockIdx.x, t = threadIdx.x;
  sAll[t] = gcur[t * 16];
  hst[t] = 0;
  __syncthreads();
  int cnt = min(sAll[b], BCAP);
  for (int off = 1; off < NB; off <<= 1) {
    int v = (t >= off) ? sAll[t - off] : 0;
    __syncthreads();
    sAll[t] += v;
    __syncthreads();
  }
  int base = sAll[b] - gcur[b * 16];  // exclusive prefix (true counts)
  const int* pay = &payload[b * BCAP];
  for (int i = t; i < cnt; i += 256) atomicAdd(&hst[pay[i] & 255], 1);
  __syncthreads();
  int c = hst[t];
  cur[t] = c;
  __syncthreads();
  for (int off = 1; off < NB; off <<= 1) {
    int v = (t >= off) ? cur[t - off] : 0;
    __syncthreads();
    cur[t] += v;
    __syncthreads();
  }
  int excl = cur[t] - c;
  rp[b * 256 + t] = base + excl;
  cur[t] = base + excl;
  __syncthreads();
  for (int i = t; i < cnt; i += 256) {
    int pl = pay[i];
    int p = atomicAdd(&cur[pl & 255], 1);
    srcs[p] = pl >> 8;
  }
}

// ---------------------------------------------------------------------------
// Fused Set2Set iteration: LSTM cell + attention (+ optional head).
// ---------------------------------------------------------------------------
constexpr int ACAP = 1024;  // max nodes per graph (dataset max ~330)
__global__ __launch_bounds__(256) void k_s2s(const unsigned short* __restrict__ hph,
                                             const unsigned short* __restrict__ hpl,
                                             const int* __restrict__ gp,
                                             float* __restrict__ q_star,
                                             float* __restrict__ hl,
                                             float* __restrict__ cl,
                                             const float* __restrict__ WihT,
                                             const float* __restrict__ WhhT,
                                             const float* __restrict__ b_ih,
                                             const float* __restrict__ b_hh,
                                             const float* __restrict__ W1T,
                                             const float* __restrict__ b1,
                                             const float* __restrict__ W2,
                                             const float* __restrict__ b2,
                                             float* __restrict__ outp,
                                             int first, int do_head) {
  int g = blockIdx.x;
  int t = threadIdx.x;
  int w = t >> 6, lane = t & 63;
  __shared__ float qs[128], hsh[64], gates[256];
  __shared__ float qsh[64], rsh[64];
  __shared__ float eL[ACAP];
  __shared__ float red[4];
  __shared__ float partial[4][64];
  __shared__ float asum_p[4];
  __shared__ float emax_sh;
  __shared__ float l4[4];

  // ---- LSTM cell ----
  if (t < 128) qs[t] = first ? 0.f : q_star[g * 128 + t];
  else if (t < 192) hsh[t - 128] = first ? 0.f : hl[g * 64 + (t - 128)];
  __syncthreads();
  {
    float acc = b_ih[t] + b_hh[t];
    for (int k = 0; k < 128; ++k) acc = fmaf(WihT[k * 256 + t], qs[k], acc);
    for (int k = 0; k < 64; ++k)  acc = fmaf(WhhT[k * 256 + t], hsh[k], acc);
    gates[t] = acc;
  }
  __syncthreads();
  if (t < 64) {
    float ig = sigf(gates[t]),        fg = sigf(gates[64 + t]);
    float gg = tanhf(gates[128 + t]), og = sigf(gates[192 + t]);
    float c_old = first ? 0.f : cl[g * 64 + t];
    float c = fg * c_old + ig * gg;
    float q = og * tanhf(c);
    cl[g * 64 + t] = c;
    hl[g * 64 + t] = q;
    q_star[g * 128 + t] = q;
    qsh[t] = q;
  }
  __syncthreads();

  int s = gp[g], e = gp[g + 1];
  int cnt = e - s;

  // ---- attention phase A: e_i = h[i].q ----
  int c4 = (lane & 15) * 4;
  float4 qv = {qsh[c4], qsh[c4 + 1], qsh[c4 + 2], qsh[c4 + 3]};
  for (int i0 = s + w * 4; i0 < e; i0 += 16) {
    int node = i0 + (lane >> 4);
    float p = 0.f;
    if (node < e) {
      ushort4 h4  = *(const ushort4*)&hph[(size_t)node * 64 + c4];
      ushort4 l4v = *(const ushort4*)&hpl[(size_t)node * 64 + c4];
      p = recon(h4.x, l4v.x) * qv.x + recon(h4.y, l4v.y) * qv.y +
          recon(h4.z, l4v.z) * qv.z + recon(h4.w, l4v.w) * qv.w;
    }
    p += __shfl_xor(p, 1); p += __shfl_xor(p, 2);
    p += __shfl_xor(p, 4); p += __shfl_xor(p, 8);
    if (node < e && (lane & 15) == 0) eL[node - s] = p;
  }
  __syncthreads();

  // ---- phase B: segment max ----
  float m = -INFINITY;
  for (int i = t; i < cnt; i += 256) m = fmaxf(m, eL[i]);
#pragma unroll
  for (int o = 32; o >= 1; o >>= 1) m = fmaxf(m, __shfl_xor(m, o));
  if (lane == 0) red[w] = m;
  __syncthreads();
  if (t == 0) {
    float mm = fmaxf(fmaxf(red[0], red[1]), fmaxf(red[2], red[3]));
    emax_sh = isfinite(mm) ? mm : 0.f;
  }
  __syncthreads();
  float emax = emax_sh;

  // ---- phase C: softmax-weighted feature sum ----
  float acc = 0.f, asum = 0.f;
  for (int i = s + w; i < e; i += 4) {
    float a = expf(eL[i - s] - emax);
    asum += a;
    float hv = recon(hph[(size_t)i * 64 + lane], hpl[(size_t)i * 64 + lane]);
    acc = fmaf(a, hv, acc);
  }
  partial[w][lane] = acc;
  if (lane == 0) asum_p[w] = asum;
  __syncthreads();
  if (t < 64) {
    float r  = partial[0][t] + partial[1][t] + partial[2][t] + partial[3][t];
    float as = asum_p[0] + asum_p[1] + asum_p[2] + asum_p[3];
    float rv = (cnt > 0) ? r / fmaxf(as, 1e-16f) : 0.f;
    q_star[g * 128 + 64 + t] = rv;
    rsh[t] = rv;
  }
  if (!do_head) return;
  __syncthreads();

  // ---- head ----
  if (t < 64) {
    float a1 = b1[t];
    for (int k = 0; k < 64; ++k)  a1 = fmaf(W1T[k * 64 + t], qsh[k], a1);
    for (int k = 64; k < 128; ++k) a1 = fmaf(W1T[k * 64 + t], rsh[k - 64], a1);
    hsh[t] = fmaxf(a1, 0.f);
  }
  __syncthreads();
  if (t < 4) {
    float lg = b2[t];
    for (int d = 0; d < 64; ++d) lg = fmaf(W2[t * 64 + d], hsh[d], lg);
    l4[t] = lg;
  }
  __syncthreads();
  if (t < 4) {
    float mx = fmaxf(fmaxf(l4[0], l4[1]), fmaxf(l4[2], l4[3]));
    float ssum = expf(l4[0] - mx) + expf(l4[1] - mx) + expf(l4[2] - mx) + expf(l4[3] - mx);
    outp[g * 4 + t] = l4[t] - mx - logf(ssum);
  }
}

// ---------------------------------------------------------------------------
extern "C" void kernel_launch(void* const* d_in, const int* in_sizes, int n_in,
                              void* d_out, int out_size, void* d_ws, size_t ws_size,
                              hipStream_t stream) {
  const float* x        = (const float*)d_in[0];
  const int*   eidx     = (const int*)d_in[1];
  const int*   batch    = (const int*)d_in[2];
  const float* W_mlp    = (const float*)d_in[3];
  const float* b_mlp    = (const float*)d_in[4];
  const float* W_conv   = (const float*)d_in[5];
  const float* b_conv   = (const float*)d_in[6];
  const float* gW_ih    = (const float*)d_in[7];
  const float* gW_hh    = (const float*)d_in[8];
  const float* gb_ih    = (const float*)d_in[9];
  const float* gb_hh    = (const float*)d_in[10];
  const float* lW_ih    = (const float*)d_in[11];
  const float* lW_hh    = (const float*)d_in[12];
  const float* lb_ih    = (const float*)d_in[13];
  const float* lb_hh    = (const float*)d_in[14];
  const float* W1       = (const float*)d_in[15];
  const float* b1       = (const float*)d_in[16];
  const float* W2       = (const float*)d_in[17];
  const float* b2       = (const float*)d_in[18];
  float* outp = (float*)d_out;

  // ---- workspace layout ----
  char* ws = (char*)d_ws;
  size_t off = 0;
  auto alloc = [&](size_t bytes) { size_t r = off; off = (off + bytes + 255) & ~(size_t)255; return r; };
  unsigned short* hpAh = (unsigned short*)(ws + alloc((size_t)Nn * 64 * 2));
  unsigned short* hpAl = (unsigned short*)(ws + alloc((size_t)Nn * 64 * 2));
  unsigned short* hpBh = (unsigned short*)(ws + alloc((size_t)Nn * 64 * 2));
  unsigned short* hpBl = (unsigned short*)(ws + alloc((size_t)Nn * 64 * 2));
  unsigned short* Aih  = (unsigned short*)(ws + alloc((size_t)Nn * 96 * 2));
  unsigned short* Ail  = (unsigned short*)(ws + alloc((size_t)Nn * 96 * 2));
  int*   rp    = (int*)(ws + alloc((size_t)(Nn + 1) * 4));
  int*   srcs  = (int*)(ws + alloc((size_t)Ne * 4));
  int*   gcur  = (int*)(ws + alloc((size_t)NB * 16 * 4));
  int*   payload = (int*)(ws + alloc((size_t)NB * BCAP * 4));
  int*   gp    = (int*)(ws + alloc((size_t)(Bg + 1) * 4));
  float* WihT  = (float*)(ws + alloc((size_t)128 * 256 * 4));
  float* WhhT  = (float*)(ws + alloc((size_t)64 * 256 * 4));
  float* W1T   = (float*)(ws + alloc((size_t)128 * 64 * 4));
  float* vfold = (float*)(ws + alloc(192 * 4));
  unsigned short* mlp_h = (unsigned short*)(ws + alloc(2048 * 2));
  unsigned short* mlp_l = (unsigned short*)(ws + alloc(2048 * 2));
  unsigned short* gw_h  = (unsigned short*)(ws + alloc(30720 * 2));
  unsigned short* gw_l  = (unsigned short*)(ws + alloc(30720 * 2));
  float* s2s   = (float*)(ws + alloc((size_t)Bg * (128 + 64 + 64) * 4));
  float* q_star = s2s;
  float* hl     = s2s + Bg * 128;
  float* cl     = s2s + Bg * 128 + Bg * 64;
  (void)in_sizes; (void)n_in; (void)out_size; (void)ws_size;

  hipMemsetAsync(gcur, 0, (size_t)NB * 16 * 4, stream);

  // CSR build (bucket sort) + prep (incl. W_conv folding)
  k_bucket<<<Ne / 4096, 256, 0, stream>>>(eidx, gcur, payload);
  k_placeB<<<NB, 256, 0, stream>>>(gcur, payload, rp, srcs);
  k_prepw<<<355, 256, 0, stream>>>(W_mlp, W_conv, gW_ih, gW_hh, b_conv,
                                   lW_ih, lW_hh, W1,
                                   mlp_h, mlp_l, gw_h, gw_l,
                                   WihT, WhhT, W1T, vfold, batch, gp, rp);

  // conv1 (+ x-column planes)
  k_conv1<<<Nn / 64, 256, 0, stream>>>(x, mlp_h, mlp_l, b_mlp, hpAh, hpAl, Aih, Ail);

  unsigned short *cph = hpAh, *cpl = hpAl, *nph = hpBh, *npl = hpBl;
  for (int step = 0; step < 2; ++step) {
    k_gru<<<Nn / 128, 256, 0, stream>>>(Aih, Ail, cph, cpl, gw_h, gw_l,
                                        gb_ih, gb_hh, vfold, rp, srcs, nph, npl);
    unsigned short* tu;
    tu = cph; cph = nph; nph = tu;
    tu = cpl; cpl = npl; npl = tu;
  }

  for (int it = 0; it < 3; ++it) {
    k_s2s<<<Bg, 256, 0, stream>>>(cph, cpl, gp, q_star, hl, cl, WihT, WhhT,
                                  lb_ih, lb_hh, W1T, b1, W2, b2, outp,
                                  it == 0 ? 1 : 0, it == 2 ? 1 : 0);
  }
}

// Round 16
// 330.182 us; speedup vs baseline: 1.1252x; 1.1252x over previous
//
#include <hip/hip_runtime.h>
#include <math.h>

constexpr int Nn  = 65536;    // nodes
constexpr int Ne  = 1048576;  // edges
constexpr int Bg  = 256;      // graphs
constexpr int DIN = 32;
constexpr int D   = 64;

constexpr int NB   = 256;     // dst buckets (dst>>8)
constexpr int BCAP = 6144;    // bucket stream capacity (mean 4096, +36 sigma)

typedef __attribute__((ext_vector_type(8))) short bf16x8;
typedef __attribute__((ext_vector_type(8))) unsigned short u16x8;
typedef __attribute__((ext_vector_type(4))) float f32x4;

__device__ __forceinline__ float sigf(float x) { return 1.0f / (1.0f + expf(-x)); }

// ---- bf16 split helpers (RNE) ----
__device__ __forceinline__ unsigned short bf16_rne(float f) {
  unsigned u = __float_as_uint(f);
  unsigned r = u + 0x7FFFu + ((u >> 16) & 1u);
  return (unsigned short)(r >> 16);
}
__device__ __forceinline__ float bf16_tof(unsigned short h) {
  return __uint_as_float(((unsigned)h) << 16);
}
__device__ __forceinline__ void split2(float f, unsigned short& hi, unsigned short& lo) {
  hi = bf16_rne(f);
  lo = bf16_rne(f - bf16_tof(hi));
}
__device__ __forceinline__ float recon(unsigned short hi, unsigned short lo) {
  return bf16_tof(hi) + bf16_tof(lo);
}

#define MFMA(a, b, c) __builtin_amdgcn_mfma_f32_16x16x32_bf16(a, b, c, 0, 0, 0)

// ---------------------------------------------------------------------------
// Prep.  GRU weights chunk-major (5 chunks x 12nt x 64lane x 8j / plane):
//   chunks 0,1 = Wfold = Wih[:, :64] @ W_conv   (fused conv-linear)
//   chunk  2   = Wih[:, 64:96]  (x part)
//   chunks 3,4 = Whh
// Also: W_mlp pack, LSTM/W1 transposes, graphptr, rp[Nn], vfold.
// ---------------------------------------------------------------------------
__global__ void k_prepw(const float* __restrict__ W_mlp, const float* __restrict__ W_conv,
                        const float* __restrict__ gWih, const float* __restrict__ gWhh,
                        const float* __restrict__ b_conv,
                        const float* __restrict__ lW_ih, const float* __restrict__ lW_hh,
                        const float* __restrict__ W1,
                        unsigned short* __restrict__ mlp_h, unsigned short* __restrict__ mlp_l,
                        unsigned short* __restrict__ gw_h,  unsigned short* __restrict__ gw_l,
                        float* __restrict__ WihT, float* __restrict__ WhhT,
                        float* __restrict__ W1T, float* __restrict__ vfold,
                        const int* __restrict__ batch, int* __restrict__ gp,
                        int* __restrict__ rp) {
  int idx = blockIdx.x * 256 + threadIdx.x;
  if (idx < 30720) {  // GRU weights, chunk-major
    int c = idx / 6144, rem = idx % 6144;
    int nt = rem >> 9, lane = (rem >> 3) & 63, j = rem & 7;
    int n = nt * 16 + (lane & 15);
    int kk = c * 32 + (lane >> 4) * 8 + j;   // for c<3: k index into [S|x]
    float v;
    if (c < 2) {        // Wfold[n][kk] = sum_o Wih[n][o] * W_conv[o][kk]
      float s = 0.f;
      for (int o = 0; o < 64; ++o) s = fmaf(gWih[n * 96 + o], W_conv[o * 64 + kk], s);
      v = s;
    } else if (c == 2) {
      v = gWih[n * 96 + kk];                 // kk in 64..95 (x columns)
    } else {
      v = gWhh[n * 64 + (c - 3) * 32 + (lane >> 4) * 8 + j];
    }
    unsigned short hi, lo; split2(v, hi, lo);
    gw_h[idx] = hi; gw_l[idx] = lo;
    return;
  }
  if (idx < 32768) {  // W_mlp (KS=1)
    int lp = idx - 30720;
    int nt = lp >> 9, lane = (lp >> 3) & 63, j = lp & 7;
    int n = nt * 16 + (lane & 15);
    unsigned short hi, lo;
    split2(W_mlp[n * 32 + (lane >> 4) * 8 + j], hi, lo);
    mlp_h[lp] = hi; mlp_l[lp] = lo;
    return;
  }
  int t = idx - 32768;
  if (t < 32768) {                 // lstm W_ih [256][128] -> WihT [128][256]
    int row = t / 128, k = t % 128;
    WihT[k * 256 + row] = lW_ih[t];
  } else if (t < 49152) {          // lstm W_hh [256][64] -> WhhT [64][256]
    int j = t - 32768;
    int row = j / 64, k = j % 64;
    WhhT[k * 256 + row] = lW_hh[j];
  } else if (t < 57344) {          // W1 [64][128] -> W1T [128][64]
    int j = t - 49152;
    int row = j / 128, k = j % 128;
    W1T[k * 64 + row] = W1[j];
  } else if (t < 57344 + Bg + 1) { // graphptr + rp[Nn]
    int g = t - 57344;
    if (g == 0) rp[Nn] = Ne;
    int lo = 0, hi = Nn;
    while (lo < hi) {
      int mid = (lo + hi) >> 1;
      if (batch[mid] < g) lo = mid + 1; else hi = mid;
    }
    gp[g] = lo;
  } else if (t < 57344 + 257 + 192) { // vfold[192]
    int g = t - 57344 - 257;
    float s = 0.f;
    for (int o = 0; o < 64; ++o) s = fmaf(gWih[g * 96 + o], b_conv[o], s);
    vfold[g] = s;
  }
}

// ---------------------------------------------------------------------------
// conv1: h = x @ W_mlp^T + b  (K=32, N=64). Splits x in-kernel; also fills
// inp96 x-columns (64..95).  h stored as planes only.
// ---------------------------------------------------------------------------
__global__ __launch_bounds__(256) void k_conv1(const float* __restrict__ x,
                                               const unsigned short* __restrict__ Wh,
                                               const unsigned short* __restrict__ Wl,
                                               const float* __restrict__ bias,
                                               unsigned short* __restrict__ hph,
                                               unsigned short* __restrict__ hpl,
                                               unsigned short* __restrict__ Aih,
                                               unsigned short* __restrict__ Ail) {
  int wave = threadIdx.x >> 6, lane = threadIdx.x & 63;
  int quad = lane >> 4;
  int n0w = blockIdx.x * 64 + wave * 16;
  int rowA = n0w + (lane & 15);
  const float4* xp = (const float4*)&x[(size_t)rowA * 32 + quad * 8];
  float4 xa = xp[0], xb = xp[1];
  float xv[8] = {xa.x, xa.y, xa.z, xa.w, xb.x, xb.y, xb.z, xb.w};
  bf16x8 ah, al;
#pragma unroll
  for (int j = 0; j < 8; ++j) {
    unsigned short hi, lo; split2(xv[j], hi, lo);
    ah[j] = (short)hi; al[j] = (short)lo;
  }
  *(bf16x8*)&Aih[(size_t)rowA * 96 + 64 + quad * 8] = ah;
  *(bf16x8*)&Ail[(size_t)rowA * 96 + 64 + quad * 8] = al;

  f32x4 acc[4] = {};
#pragma unroll
  for (int nt = 0; nt < 4; ++nt) {
    bf16x8 bh = *(const bf16x8*)&Wh[(nt * 64 + lane) * 8];
    bf16x8 bl = *(const bf16x8*)&Wl[(nt * 64 + lane) * 8];
    acc[nt] = MFMA(ah, bh, acc[nt]);
    acc[nt] = MFMA(ah, bl, acc[nt]);
    acc[nt] = MFMA(al, bh, acc[nt]);
  }
  int col0 = lane & 15;
#pragma unroll
  for (int nt = 0; nt < 4; ++nt) {
    float bv = bias[nt * 16 + col0];
#pragma unroll
    for (int r = 0; r < 4; ++r) {
      int node = n0w + quad * 4 + r;
      float v = acc[nt][r] + bv;
      size_t o = (size_t)node * 64 + nt * 16 + col0;
      unsigned short hi, lo; split2(v, hi, lo);
      hph[o] = hi; hpl[o] = lo;
    }
  }
}

// ---------------------------------------------------------------------------
// Fused GRU v7 (round-14 best): aggregate fused in.  Each lane gathers its
// MFMA A-fragment slices of S = sum_{src} bf16(h[src]) directly from Hh via
// CSR (two 16 B slices per row; a wave's 64 lanes cover 16 rows x full
// 128 B lines), then runs the 5-chunk double-buffered-LDS K-loop with
// chunks 0/1 fed from the gathered register fragments.
// (256,2): VGPR 124 + MFMA accumulators fits 2 blocks/CU; (256,3) spills.
// ---------------------------------------------------------------------------
__global__ __launch_bounds__(256, 2) void k_gru(const unsigned short* __restrict__ Aih,
                                                const unsigned short* __restrict__ Ail,
                                                const unsigned short* __restrict__ Hh,
                                                const unsigned short* __restrict__ Hl,
                                                const unsigned short* __restrict__ gw_h,
                                                const unsigned short* __restrict__ gw_l,
                                                const float* __restrict__ b_ih,
                                                const float* __restrict__ b_hh,
                                                const float* __restrict__ vfold,
                                                const int* __restrict__ rp,
                                                const int* __restrict__ srcs,
                                                unsigned short* __restrict__ nph,
                                                unsigned short* __restrict__ npl) {
  __shared__ unsigned short sW[2][12288];  // per buf: hi[0..6143] | lo[6144..]
  int tid = threadIdx.x;
  int wave = tid >> 6, lane = tid & 63;
  int quad = lane >> 4;
  int n0w = blockIdx.x * 128 + wave * 32;
  int rowA0 = n0w + (lane & 15);          // tile0 A-row; tile1 = +16

  // ---- fused aggregate: gather S fragments for chunks 0,1, both tiles ----
  bf16x8 fh[2][2], fl[2][2];  // [tile][chunk]
#pragma unroll
  for (int tile = 0; tile < 2; ++tile) {
    int row = rowA0 + tile * 16;
    int s = rp[row], e = rp[row + 1];
    float acc0[8] = {}, acc1[8] = {};
    for (int i = s; i < e; ++i) {
      int src = srcs[i];
      u16x8 v0 = *(const u16x8*)&Hh[(size_t)src * 64 + quad * 8];
      u16x8 v1 = *(const u16x8*)&Hh[(size_t)src * 64 + 32 + quad * 8];
#pragma unroll
      for (int j = 0; j < 8; ++j) {
        acc0[j] += bf16_tof(v0[j]);
        acc1[j] += bf16_tof(v1[j]);
      }
    }
#pragma unroll
    for (int j = 0; j < 8; ++j) {
      unsigned short hi, lo;
      split2(acc0[j], hi, lo);
      fh[tile][0][j] = (short)hi; fl[tile][0][j] = (short)lo;
      split2(acc1[j], hi, lo);
      fh[tile][1][j] = (short)hi; fl[tile][1][j] = (short)lo;
    }
  }

  f32x4 acc0[12] = {}, acc1[12] = {};     // gi r,z,n (gh r,z folded into 0..7)
  f32x4 aN0[4] = {}, aN1[4] = {};         // gh n-gate

  // prologue: weights chunk 0
  bf16x8 gvh[3], gvl[3];
#pragma unroll
  for (int j = 0; j < 3; ++j) {
    gvh[j] = *(const bf16x8*)&gw_h[(tid + j * 256) * 8];
    gvl[j] = *(const bf16x8*)&gw_l[(tid + j * 256) * 8];
  }
#pragma unroll
  for (int j = 0; j < 3; ++j) {
    *(bf16x8*)&sW[0][(tid + j * 256) * 8] = gvh[j];
    *(bf16x8*)&sW[0][6144 + (tid + j * 256) * 8] = gvl[j];
  }
  __syncthreads();

#pragma unroll
  for (int c = 0; c < 5; ++c) {
    const int buf = c & 1;
    if (c < 4) {  // prefetch chunk c+1 weights
#pragma unroll
      for (int j = 0; j < 3; ++j) {
        gvh[j] = *(const bf16x8*)&gw_h[(c + 1) * 6144 + (tid + j * 256) * 8];
        gvl[j] = *(const bf16x8*)&gw_l[(c + 1) * 6144 + (tid + j * 256) * 8];
      }
    }
    // A fragments
    bf16x8 a0h, a0l, a1h, a1l;
    if (c < 2) {            // gathered S fragments (registers)
      a0h = fh[0][c]; a0l = fl[0][c];
      a1h = fh[1][c]; a1l = fl[1][c];
    } else if (c == 2) {    // x columns from conv1 prep
      size_t b0 = (size_t)rowA0 * 96 + 64 + quad * 8;
      size_t b1 = (size_t)(rowA0 + 16) * 96 + 64 + quad * 8;
      a0h = *(const bf16x8*)&Aih[b0]; a0l = *(const bf16x8*)&Ail[b0];
      a1h = *(const bf16x8*)&Aih[b1]; a1l = *(const bf16x8*)&Ail[b1];
    } else {                // h planes (Whh chunks)
      size_t b0 = (size_t)rowA0 * 64 + (c - 3) * 32 + quad * 8;
      size_t b1 = (size_t)(rowA0 + 16) * 64 + (c - 3) * 32 + quad * 8;
      a0h = *(const bf16x8*)&Hh[b0]; a0l = *(const bf16x8*)&Hl[b0];
      a1h = *(const bf16x8*)&Hh[b1]; a1l = *(const bf16x8*)&Hl[b1];
    }
    const unsigned short* sw = sW[buf];
#pragma unroll
    for (int nt = 0; nt < 12; ++nt) {
      bf16x8 bh = *(const bf16x8*)&sw[(nt * 64 + lane) * 8];
      bf16x8 bl = *(const bf16x8*)&sw[6144 + (nt * 64 + lane) * 8];
      if (c < 3 || nt < 8) {
        acc0[nt] = MFMA(a0h, bh, acc0[nt]);
        acc0[nt] = MFMA(a0h, bl, acc0[nt]);
        acc0[nt] = MFMA(a0l, bh, acc0[nt]);
        acc1[nt] = MFMA(a1h, bh, acc1[nt]);
        acc1[nt] = MFMA(a1h, bl, acc1[nt]);
        acc1[nt] = MFMA(a1l, bh, acc1[nt]);
      } else {
        aN0[nt - 8] = MFMA(a0h, bh, aN0[nt - 8]);
        aN0[nt - 8] = MFMA(a0h, bl, aN0[nt - 8]);
        aN0[nt - 8] = MFMA(a0l, bh, aN0[nt - 8]);
        aN1[nt - 8] = MFMA(a1h, bh, aN1[nt - 8]);
        aN1[nt - 8] = MFMA(a1h, bl, aN1[nt - 8]);
        aN1[nt - 8] = MFMA(a1l, bh, aN1[nt - 8]);
      }
    }
    if (c < 4) {
#pragma unroll
      for (int j = 0; j < 3; ++j) {
        *(bf16x8*)&sW[1 - buf][(tid + j * 256) * 8] = gvh[j];
        *(bf16x8*)&sW[1 - buf][6144 + (tid + j * 256) * 8] = gvl[j];
      }
    }
    __syncthreads();
  }

  // epilogue: GRU nonlinearity + deg*vfold (folded conv bias) + plane store
  int col0 = lane & 15;
#pragma unroll
  for (int tile = 0; tile < 2; ++tile) {
    int nb = n0w + tile * 16;
#pragma unroll
    for (int r = 0; r < 4; ++r) {
      int node = nb + quad * 4 + r;
      float degf = (float)(rp[node + 1] - rp[node]);
#pragma unroll
      for (int nt = 0; nt < 4; ++nt) {
        int g = nt * 16 + col0;
        size_t o = (size_t)node * 64 + g;
        float br  = b_ih[g] + b_hh[g] + degf * vfold[g];
        float bz  = b_ih[64 + g] + b_hh[64 + g] + degf * vfold[64 + g];
        float bin = b_ih[128 + g] + degf * vfold[128 + g];
        float bhn = b_hh[128 + g];
        float gr = tile ? acc1[nt][r]     : acc0[nt][r];
        float gz = tile ? acc1[nt + 4][r] : acc0[nt + 4][r];
        float gn = tile ? acc1[nt + 8][r] : acc0[nt + 8][r];
        float hn = tile ? aN1[nt][r]      : aN0[nt][r];
        float rr = sigf(gr + br);
        float zz = sigf(gz + bz);
        float nn = tanhf(gn + bin + rr * (hn + bhn));
        float h_old = recon(Hh[o], Hl[o]);
        float hv = (1.f - zz) * nn + zz * h_old;
        unsigned short hi, lo; split2(hv, hi, lo);
        nph[o] = hi; npl[o] = lo;
      }
    }
  }
}

// ---------------------------------------------------------------------------
// CSR build v3: two-level bucket sort by dst.
// ---------------------------------------------------------------------------
__global__ __launch_bounds__(256) void k_bucket(const int* __restrict__ eidx,
                                                int* __restrict__ gcur,     // [NB*16]
                                                int* __restrict__ payload) {// [NB*BCAP]
  __shared__ int lcnt[NB];
  __shared__ int lcur[NB];
  int t = threadIdx.x;
  int e0 = blockIdx.x * 4096;
  lcnt[t] = 0;
  __syncthreads();
  int ds[16], ss[16];
#pragma unroll
  for (int i = 0; i < 16; ++i) {
    int e = e0 + i * 256 + t;
    ds[i] = eidx[Ne + e];
    ss[i] = eidx[e];
    atomicAdd(&lcnt[ds[i] >> 8], 1);
  }
  __syncthreads();
  lcur[t] = atomicAdd(&gcur[t * 16], lcnt[t]);  // reserve contiguous run
  __syncthreads();
#pragma unroll
  for (int i = 0; i < 16; ++i) {
    int b = ds[i] >> 8;
    int p = atomicAdd(&lcur[b], 1);
    if (p < BCAP) payload[b * BCAP + p] = (ss[i] << 8) | (ds[i] & 255);
  }
}

// One block per bucket: inline scan of gcur -> base, LDS hist -> rp slice,
// place srcs via LDS cursors (scatter window owned by one CU).
__global__ __launch_bounds__(256) void k_placeB(const int* __restrict__ gcur,
                                                const int* __restrict__ payload,
                                                int* __restrict__ rp,
                                                int* __restrict__ srcs) {
  __shared__ int sAll[NB];
  __shared__ int hst[NB];
  __shared__ int cur[NB];
  int b = blockIdx.x, t = threadIdx.x;
  sAll[t] = gcur[t * 16];
  hst[t] = 0;
  __syncthreads();
  int cnt = min(sAll[b], BCAP);
  for (int off = 1; off < NB; off <<= 1) {
    int v = (t >= off) ? sAll[t - off] : 0;
    __syncthreads();
    sAll[t] += v;
    __syncthreads();
  }
  int base = sAll[b] - gcur[b * 16];  // exclusive prefix (true counts)
  const int* pay = &payload[b * BCAP];
  for (int i = t; i < cnt; i += 256) atomicAdd(&hst[pay[i] & 255], 1);
  __syncthreads();
  int c = hst[t];
  cur[t] = c;
  __syncthreads();
  for (int off = 1; off < NB; off <<= 1) {
    int v = (t >= off) ? cur[t - off] : 0;
    __syncthreads();
    cur[t] += v;
    __syncthreads();
  }
  int excl = cur[t] - c;
  rp[b * 256 + t] = base + excl;
  cur[t] = base + excl;
  __syncthreads();
  for (int i = t; i < cnt; i += 256) {
    int pl = pay[i];
    int p = atomicAdd(&cur[pl & 255], 1);
    srcs[p] = pl >> 8;
  }
}

// ---------------------------------------------------------------------------
// Fused Set2Set iteration: LSTM cell + attention (+ optional head).
// ---------------------------------------------------------------------------
constexpr int ACAP = 1024;  // max nodes per graph (dataset max ~330)
__global__ __launch_bounds__(256) void k_s2s(const unsigned short* __restrict__ hph,
                                             const unsigned short* __restrict__ hpl,
                                             const int* __restrict__ gp,
                                             float* __restrict__ q_star,
                                             float* __restrict__ hl,
                                             float* __restrict__ cl,
                                             const float* __restrict__ WihT,
                                             const float* __restrict__ WhhT,
                                             const float* __restrict__ b_ih,
                                             const float* __restrict__ b_hh,
                                             const float* __restrict__ W1T,
                                             const float* __restrict__ b1,
                                             const float* __restrict__ W2,
                                             const float* __restrict__ b2,
                                             float* __restrict__ outp,
                                             int first, int do_head) {
  int g = blockIdx.x;
  int t = threadIdx.x;
  int w = t >> 6, lane = t & 63;
  __shared__ float qs[128], hsh[64], gates[256];
  __shared__ float qsh[64], rsh[64];
  __shared__ float eL[ACAP];
  __shared__ float red[4];
  __shared__ float partial[4][64];
  __shared__ float asum_p[4];
  __shared__ float emax_sh;
  __shared__ float l4[4];

  // ---- LSTM cell ----
  if (t < 128) qs[t] = first ? 0.f : q_star[g * 128 + t];
  else if (t < 192) hsh[t - 128] = first ? 0.f : hl[g * 64 + (t - 128)];
  __syncthreads();
  {
    float acc = b_ih[t] + b_hh[t];
    for (int k = 0; k < 128; ++k) acc = fmaf(WihT[k * 256 + t], qs[k], acc);
    for (int k = 0; k < 64; ++k)  acc = fmaf(WhhT[k * 256 + t], hsh[k], acc);
    gates[t] = acc;
  }
  __syncthreads();
  if (t < 64) {
    float ig = sigf(gates[t]),        fg = sigf(gates[64 + t]);
    float gg = tanhf(gates[128 + t]), og = sigf(gates[192 + t]);
    float c_old = first ? 0.f : cl[g * 64 + t];
    float c = fg * c_old + ig * gg;
    float q = og * tanhf(c);
    cl[g * 64 + t] = c;
    hl[g * 64 + t] = q;
    q_star[g * 128 + t] = q;
    qsh[t] = q;
  }
  __syncthreads();

  int s = gp[g], e = gp[g + 1];
  int cnt = e - s;

  // ---- attention phase A: e_i = h[i].q ----
  int c4 = (lane & 15) * 4;
  float4 qv = {qsh[c4], qsh[c4 + 1], qsh[c4 + 2], qsh[c4 + 3]};
  for (int i0 = s + w * 4; i0 < e; i0 += 16) {
    int node = i0 + (lane >> 4);
    float p = 0.f;
    if (node < e) {
      ushort4 h4  = *(const ushort4*)&hph[(size_t)node * 64 + c4];
      ushort4 l4v = *(const ushort4*)&hpl[(size_t)node * 64 + c4];
      p = recon(h4.x, l4v.x) * qv.x + recon(h4.y, l4v.y) * qv.y +
          recon(h4.z, l4v.z) * qv.z + recon(h4.w, l4v.w) * qv.w;
    }
    p += __shfl_xor(p, 1); p += __shfl_xor(p, 2);
    p += __shfl_xor(p, 4); p += __shfl_xor(p, 8);
    if (node < e && (lane & 15) == 0) eL[node - s] = p;
  }
  __syncthreads();

  // ---- phase B: segment max ----
  float m = -INFINITY;
  for (int i = t; i < cnt; i += 256) m = fmaxf(m, eL[i]);
#pragma unroll
  for (int o = 32; o >= 1; o >>= 1) m = fmaxf(m, __shfl_xor(m, o));
  if (lane == 0) red[w] = m;
  __syncthreads();
  if (t == 0) {
    float mm = fmaxf(fmaxf(red[0], red[1]), fmaxf(red[2], red[3]));
    emax_sh = isfinite(mm) ? mm : 0.f;
  }
  __syncthreads();
  float emax = emax_sh;

  // ---- phase C: softmax-weighted feature sum ----
  float acc = 0.f, asum = 0.f;
  for (int i = s + w; i < e; i += 4) {
    float a = expf(eL[i - s] - emax);
    asum += a;
    float hv = recon(hph[(size_t)i * 64 + lane], hpl[(size_t)i * 64 + lane]);
    acc = fmaf(a, hv, acc);
  }
  partial[w][lane] = acc;
  if (lane == 0) asum_p[w] = asum;
  __syncthreads();
  if (t < 64) {
    float r  = partial[0][t] + partial[1][t] + partial[2][t] + partial[3][t];
    float as = asum_p[0] + asum_p[1] + asum_p[2] + asum_p[3];
    float rv = (cnt > 0) ? r / fmaxf(as, 1e-16f) : 0.f;
    q_star[g * 128 + 64 + t] = rv;
    rsh[t] = rv;
  }
  if (!do_head) return;
  __syncthreads();

  // ---- head ----
  if (t < 64) {
    float a1 = b1[t];
    for (int k = 0; k < 64; ++k)  a1 = fmaf(W1T[k * 64 + t], qsh[k], a1);
    for (int k = 64; k < 128; ++k) a1 = fmaf(W1T[k * 64 + t], rsh[k - 64], a1);
    hsh[t] = fmaxf(a1, 0.f);
  }
  __syncthreads();
  if (t < 4) {
    float lg = b2[t];
    for (int d = 0; d < 64; ++d) lg = fmaf(W2[t * 64 + d], hsh[d], lg);
    l4[t] = lg;
  }
  __syncthreads();
  if (t < 4) {
    float mx = fmaxf(fmaxf(l4[0], l4[1]), fmaxf(l4[2], l4[3]));
    float ssum = expf(l4[0] - mx) + expf(l4[1] - mx) + expf(l4[2] - mx) + expf(l4[3] - mx);
    outp[g * 4 + t] = l4[t] - mx - logf(ssum);
  }
}

// ---------------------------------------------------------------------------
extern "C" void kernel_launch(void* const* d_in, const int* in_sizes, int n_in,
                              void* d_out, int out_size, void* d_ws, size_t ws_size,
                              hipStream_t stream) {
  const float* x        = (const float*)d_in[0];
  const int*   eidx     = (const int*)d_in[1];
  const int*   batch    = (const int*)d_in[2];
  const float* W_mlp    = (const float*)d_in[3];
  const float* b_mlp    = (const float*)d_in[4];
  const float* W_conv   = (const float*)d_in[5];
  const float* b_conv   = (const float*)d_in[6];
  const float* gW_ih    = (const float*)d_in[7];
  const float* gW_hh    = (const float*)d_in[8];
  const float* gb_ih    = (const float*)d_in[9];
  const float* gb_hh    = (const float*)d_in[10];
  const float* lW_ih    = (const float*)d_in[11];
  const float* lW_hh    = (const float*)d_in[12];
  const float* lb_ih    = (const float*)d_in[13];
  const float* lb_hh    = (const float*)d_in[14];
  const float* W1       = (const float*)d_in[15];
  const float* b1       = (const float*)d_in[16];
  const float* W2       = (const float*)d_in[17];
  const float* b2       = (const float*)d_in[18];
  float* outp = (float*)d_out;

  // ---- workspace layout ----
  char* ws = (char*)d_ws;
  size_t off = 0;
  auto alloc = [&](size_t bytes) { size_t r = off; off = (off + bytes + 255) & ~(size_t)255; return r; };
  unsigned short* hpAh = (unsigned short*)(ws + alloc((size_t)Nn * 64 * 2));
  unsigned short* hpAl = (unsigned short*)(ws + alloc((size_t)Nn * 64 * 2));
  unsigned short* hpBh = (unsigned short*)(ws + alloc((size_t)Nn * 64 * 2));
  unsigned short* hpBl = (unsigned short*)(ws + alloc((size_t)Nn * 64 * 2));
  unsigned short* Aih  = (unsigned short*)(ws + alloc((size_t)Nn * 96 * 2));
  unsigned short* Ail  = (unsigned short*)(ws + alloc((size_t)Nn * 96 * 2));
  int*   rp    = (int*)(ws + alloc((size_t)(Nn + 1) * 4));
  int*   srcs  = (int*)(ws + alloc((size_t)Ne * 4));
  int*   gcur  = (int*)(ws + alloc((size_t)NB * 16 * 4));
  int*   payload = (int*)(ws + alloc((size_t)NB * BCAP * 4));
  int*   gp    = (int*)(ws + alloc((size_t)(Bg + 1) * 4));
  float* WihT  = (float*)(ws + alloc((size_t)128 * 256 * 4));
  float* WhhT  = (float*)(ws + alloc((size_t)64 * 256 * 4));
  float* W1T   = (float*)(ws + alloc((size_t)128 * 64 * 4));
  float* vfold = (float*)(ws + alloc(192 * 4));
  unsigned short* mlp_h = (unsigned short*)(ws + alloc(2048 * 2));
  unsigned short* mlp_l = (unsigned short*)(ws + alloc(2048 * 2));
  unsigned short* gw_h  = (unsigned short*)(ws + alloc(30720 * 2));
  unsigned short* gw_l  = (unsigned short*)(ws + alloc(30720 * 2));
  float* s2s   = (float*)(ws + alloc((size_t)Bg * (128 + 64 + 64) * 4));
  float* q_star = s2s;
  float* hl     = s2s + Bg * 128;
  float* cl     = s2s + Bg * 128 + Bg * 64;
  (void)in_sizes; (void)n_in; (void)out_size; (void)ws_size;

  hipMemsetAsync(gcur, 0, (size_t)NB * 16 * 4, stream);

  // CSR build (bucket sort) + prep (incl. W_conv folding)
  k_bucket<<<Ne / 4096, 256, 0, stream>>>(eidx, gcur, payload);
  k_placeB<<<NB, 256, 0, stream>>>(gcur, payload, rp, srcs);
  k_prepw<<<355, 256, 0, stream>>>(W_mlp, W_conv, gW_ih, gW_hh, b_conv,
                                   lW_ih, lW_hh, W1,
                                   mlp_h, mlp_l, gw_h, gw_l,
                                   WihT, WhhT, W1T, vfold, batch, gp, rp);

  // conv1 (+ x-column planes)
  k_conv1<<<Nn / 64, 256, 0, stream>>>(x, mlp_h, mlp_l, b_mlp, hpAh, hpAl, Aih, Ail);

  unsigned short *cph = hpAh, *cpl = hpAl, *nph = hpBh, *npl = hpBl;
  for (int step = 0; step < 2; ++step) {
    k_gru<<<Nn / 128, 256, 0, stream>>>(Aih, Ail, cph, cpl, gw_h, gw_l,
                                        gb_ih, gb_hh, vfold, rp, srcs, nph, npl);
    unsigned short* tu;
    tu = cph; cph = nph; nph = tu;
    tu = cpl; cpl = npl; npl = tu;
  }

  for (int it = 0; it < 3; ++it) {
    k_s2s<<<Bg, 256, 0, stream>>>(cph, cpl, gp, q_star, hl, cl, WihT, WhhT,
                                  lb_ih, lb_hh, W1T, b1, W2, b2, outp,
                                  it == 0 ? 1 : 0, it == 2 ? 1 : 0);
  }
}